// Round 6
// baseline (137.978 us; speedup 1.0000x reference)
//
#include <hip/hip_runtime.h>

typedef _Float16 f16;
typedef __attribute__((ext_vector_type(8))) _Float16 f16x8;
typedef __attribute__((ext_vector_type(4))) float f32x4;

#define NSEQ 16
#define QL   128
#define NH   8
#define NG   4
#define DH   128
#define PGSZ 64
#define PPS  16
#define KT   64      // kv tile == page size (one scalar page lookup per tile)
#define QIB  32      // query indices per block
#define THR_DEFER 11.0f   // defer-max threshold in log2 domain (~7.6 nats)

// Barrier with LDS-visibility only (no vmcnt drain): in-flight global
// prefetch loads stay outstanding across it.
__device__ __forceinline__ void bar_lds() {
    asm volatile("s_waitcnt lgkmcnt(0)" ::: "memory");
    __builtin_amdgcn_s_barrier();
    asm volatile("" ::: "memory");
}

// DPP row_ror:N within 16-lane rows — cross-lane reduce on the VALU pipe,
// zero DS-pipe traffic (replaces ds_swizzle-based __shfl_xor).
template<int N>
__device__ __forceinline__ float rowror(float x) {
    int t = __builtin_amdgcn_update_dpp(__float_as_int(x), __float_as_int(x),
                                        0x120 | N, 0xF, 0xF, false);
    return __int_as_float(t);
}
__device__ __forceinline__ float rmax16(float x) {
    x = fmaxf(x, rowror<1>(x));
    x = fmaxf(x, rowror<2>(x));
    x = fmaxf(x, rowror<4>(x));
    x = fmaxf(x, rowror<8>(x));
    return x;
}
__device__ __forceinline__ float rsum16(float x) {
    x += rowror<1>(x);
    x += rowror<2>(x);
    x += rowror<4>(x);
    x += rowror<8>(x);
    return x;
}

__device__ __forceinline__ float fexp2(float x) {
    return __builtin_amdgcn_exp2f(x);
}

__global__ __launch_bounds__(256, 2)
void rpa_fwd(const float* __restrict__ q,
             const float* __restrict__ kv_pages,
             const int* __restrict__ kv_lens,
             const int* __restrict__ page_indices,
             float* __restrict__ out)
{
    const int tid  = threadIdx.x;
    const int w    = tid >> 6;    // wave 0..3, owns q-rows [w*32, w*32+32)
    const int lane = tid & 63;
    const int c16  = lane & 15;
    const int g16  = lane >> 4;

    const int qt = blockIdx.x;    // 0..3
    const int h  = blockIdx.y;    // 0..7
    const int s  = blockIdx.z;    // 0..15

    const int kv_len = kv_lens[s];
    const int kv_end = kv_len - QL + qt*QIB + QIB;   // exclusive kv bound
    const int ntile  = (kv_end + KT - 1) >> 6;

    // Un-padded rows + XOR slot swizzle (slot ^= row&7) -> conflict-free b128
    __shared__ f16 Klds [KT][DH];      // 64 rows x 256B
    __shared__ f16 VTlds[DH][KT];      // 128 rows x 128B (V transposed)
    __shared__ f16 Plds [4][QIB][KT];  // per-wave P, 32 rows x 128B

    // staging maps (256 threads)
    const int kr  = tid >> 2;          // K row 0..63
    const int kq  = (tid & 3) * 32;    // K f32 col base (32 floats/thread)
    const int vp  = tid & 31;          // V kv-pair -> kv = 2vp, 2vp+1
    const int vd0 = (tid >> 5) * 16;   // V d base (16 d/thread)

    // ---- Q fragments for 2 q-halves, pre-scaled by (1/sqrt(D))*log2(e)
    f16x8 qfrag[2][4];
    {
        const float sc = 0.08838834764831845f * 1.4426950408889634f;
        #pragma unroll
        for (int h2 = 0; h2 < 2; ++h2) {
            const int rowA = h2*16 + c16;
            const int qiA  = qt*QIB + w*8 + (rowA >> 2);
            const int gA   = rowA & 3;
            const float* qp = q + (((size_t)(s*QL + qiA)*NH + h)*NG + gA)*DH;
            #pragma unroll
            for (int sl = 0; sl < 4; ++sl) {
                const float* p = qp + sl*32 + g16*8;
                f32x4 a = *(const f32x4*)p;
                f32x4 b = *(const f32x4*)(p + 4);
                f16x8 f;
                f[0]=(f16)(a[0]*sc); f[1]=(f16)(a[1]*sc); f[2]=(f16)(a[2]*sc); f[3]=(f16)(a[3]*sc);
                f[4]=(f16)(b[0]*sc); f[5]=(f16)(b[1]*sc); f[6]=(f16)(b[2]*sc); f[7]=(f16)(b[3]*sc);
                qfrag[h2][sl] = f;
            }
        }
    }

    // causal positions: D-frag row (h2,g16,r) -> qi = qt*32 + w*8 + h2*4 + g16
    int qp2[2];
    qp2[0] = kv_len - QL + qt*QIB + w*8 + g16;
    qp2[1] = qp2[0] + 4;
    const int qp_wave_min = kv_len - QL + qt*QIB + w*8;

    f32x4 oacc[2][8];
    #pragma unroll
    for (int h2 = 0; h2 < 2; ++h2)
        #pragma unroll
        for (int f = 0; f < 8; ++f) oacc[h2][f] = f32x4{0.f,0.f,0.f,0.f};
    float mrun[2][4], lrun[2][4];
    #pragma unroll
    for (int h2 = 0; h2 < 2; ++h2)
        #pragma unroll
        for (int r = 0; r < 4; ++r) { mrun[h2][r] = -1e30f; lrun[h2][r] = 0.f; }

    // prefetch regs: tile t+1 in flight across compute of tile t
    f32x4 kld[8], vld[8];

#define LOAD_TILE(T) do {                                                                \
        const int pg_ = page_indices[s*PPS + (T)];                                      \
        const float* kb_ = kv_pages + (((size_t)pg_*PGSZ + kr)*(2*NH) + h)*DH + kq;     \
        _Pragma("unroll")                                                                \
        for (int i_ = 0; i_ < 8; ++i_) kld[i_] = *(const f32x4*)(kb_ + i_*4);           \
        const float* vb_ = kv_pages + (((size_t)pg_*PGSZ + 2*vp)*(2*NH) + NH + h)*DH + vd0; \
        _Pragma("unroll")                                                                \
        for (int i_ = 0; i_ < 4; ++i_) vld[i_]   = *(const f32x4*)(vb_ + i_*4);         \
        _Pragma("unroll")                                                                \
        for (int i_ = 0; i_ < 4; ++i_) vld[4+i_] = *(const f32x4*)(vb_ + 2*NH*DH + i_*4); \
    } while (0)
    // NOTE: rows >= kv_end load real (valid) memory within the page; those kv
    // are always causally masked (kv > q_pos for every row in block), so no
    // zero-fill is needed.

#define WRITE_TILE() do {                                                                \
        _Pragma("unroll")                                                                \
        for (int i_ = 0; i_ < 4; ++i_) {                                                 \
            f16x8 kk_;                                                                   \
            _Pragma("unroll")                                                            \
            for (int j_ = 0; j_ < 4; ++j_) {                                             \
                kk_[j_]   = (f16)kld[2*i_][j_];                                          \
                kk_[4+j_] = (f16)kld[2*i_+1][j_];                                        \
            }                                                                            \
            const int slot_ = (((tid&3)*4 + i_) ^ (kr & 7));                             \
            *(f16x8*)((char*)&Klds[0][0] + kr*256 + (slot_<<4)) = kk_;                   \
        }                                                                                \
        _Pragma("unroll")                                                                \
        for (int j_ = 0; j_ < 16; ++j_) {                                                \
            union { f16 hh[2]; int u; } pk_;                                             \
            pk_.hh[0] = (f16)vld[j_>>2][j_&3];                                           \
            pk_.hh[1] = (f16)vld[4+(j_>>2)][j_&3];                                       \
            *(int*)((char*)&VTlds[0][0] + (vd0+j_)*128 + ((4*vp) ^ ((j_&7)<<4))) = pk_.u;\
        }                                                                                \
    } while (0)

    LOAD_TILE(0);

    for (int t = 0; t < ntile; ++t) {
        const int kv0 = t << 6;

        WRITE_TILE();                       // vmcnt waits on prefetch regs here
        bar_lds();                          // stage visible; globals stay in flight
        if (t + 1 < ntile) LOAD_TILE(t+1);  // issue next tile, hidden under compute

        // ---- QK^T: 32 q-rows x 64 kv; 16 K reads shared across both q-halves
        f32x4 sacc[2][4];
        #pragma unroll
        for (int h2 = 0; h2 < 2; ++h2)
            #pragma unroll
            for (int ks = 0; ks < 4; ++ks) sacc[h2][ks] = f32x4{0.f,0.f,0.f,0.f};
        #pragma unroll
        for (int ks = 0; ks < 4; ++ks) {
            #pragma unroll
            for (int sl = 0; sl < 4; ++sl) {
                f16x8 kf = *(const f16x8*)((const char*)&Klds[0][0]
                            + (ks*16 + c16)*256 + ((((sl<<2)|g16) ^ (c16&7))<<4));
                sacc[0][ks] = __builtin_amdgcn_mfma_f32_16x16x32_f16(qfrag[0][sl], kf, sacc[0][ks], 0,0,0);
                sacc[1][ks] = __builtin_amdgcn_mfma_f32_16x16x32_f16(qfrag[1][sl], kf, sacc[1][ks], 0,0,0);
            }
        }

        // ---- causal mask (wave-uniform skip for interior tiles)
        if (kv0 + KT - 1 > qp_wave_min) {
            #pragma unroll
            for (int h2 = 0; h2 < 2; ++h2)
                #pragma unroll
                for (int ks = 0; ks < 4; ++ks) {
                    const bool ok = (kv0 + ks*16 + c16) <= qp2[h2];
                    #pragma unroll
                    for (int r = 0; r < 4; ++r)
                        sacc[h2][ks][r] = ok ? sacc[h2][ks][r] : -1e30f;
                }
        }

        // ---- online softmax (exp2 domain), DPP reduces, defer-max rescale
        float mt[2][4];
        bool need = false;
        #pragma unroll
        for (int h2 = 0; h2 < 2; ++h2)
            #pragma unroll
            for (int r = 0; r < 4; ++r) {
                float a = fmaxf(fmaxf(sacc[h2][0][r], sacc[h2][1][r]),
                                fmaxf(sacc[h2][2][r], sacc[h2][3][r]));
                a = rmax16(a);
                mt[h2][r] = a;
                need = need || (a > mrun[h2][r] + THR_DEFER);
            }
        if (__any(need)) {
            #pragma unroll
            for (int h2 = 0; h2 < 2; ++h2)
                #pragma unroll
                for (int r = 0; r < 4; ++r) {
                    const float mn  = fmaxf(mrun[h2][r], mt[h2][r]);
                    const float fac = fexp2(mrun[h2][r] - mn);
                    lrun[h2][r] *= fac;
                    mrun[h2][r] = mn;
                    #pragma unroll
                    for (int f = 0; f < 8; ++f) oacc[h2][f] *= fac;
                }
        }
        #pragma unroll
        for (int h2 = 0; h2 < 2; ++h2)
            #pragma unroll
            for (int r = 0; r < 4; ++r) {
                const float m = mrun[h2][r];
                float p0 = fexp2(sacc[h2][0][r] - m);
                float p1 = fexp2(sacc[h2][1][r] - m);
                float p2 = fexp2(sacc[h2][2][r] - m);
                float p3 = fexp2(sacc[h2][3][r] - m);
                lrun[h2][r] += rsum16((p0 + p1) + (p2 + p3));
                const int prow = h2*16 + g16*4 + r;
                char* pb = (char*)&Plds[w][0][0] + prow*128;
                const int key = (prow & 7) << 4;
                *(f16*)(pb + ((0*32 + 2*c16) ^ key)) = (f16)p0;
                *(f16*)(pb + ((1*32 + 2*c16) ^ key)) = (f16)p1;
                *(f16*)(pb + ((2*32 + 2*c16) ^ key)) = (f16)p2;
                *(f16*)(pb + ((3*32 + 2*c16) ^ key)) = (f16)p3;
            }

        // ---- P @ V: 16 V reads shared across both q-halves
        #pragma unroll
        for (int kvh = 0; kvh < 2; ++kvh) {
            f16x8 pf0 = *(const f16x8*)((const char*)&Plds[w][0][0]
                         + (0*16 + c16)*128 + ((((kvh<<2)|g16) ^ (c16&7))<<4));
            f16x8 pf1 = *(const f16x8*)((const char*)&Plds[w][0][0]
                         + (1*16 + c16)*128 + ((((kvh<<2)|g16) ^ (c16&7))<<4));
            #pragma unroll
            for (int f = 0; f < 8; ++f) {
                f16x8 vf = *(const f16x8*)((const char*)&VTlds[0][0]
                            + (f*16 + c16)*128 + ((((kvh<<2)|g16) ^ (c16&7))<<4));
                oacc[0][f] = __builtin_amdgcn_mfma_f32_16x16x32_f16(pf0, vf, oacc[0][f], 0,0,0);
                oacc[1][f] = __builtin_amdgcn_mfma_f32_16x16x32_f16(pf1, vf, oacc[1][f], 0,0,0);
            }
        }

        bar_lds();   // all reads of K/VT done before next WRITE_TILE
    }

    // ---- epilogue
    #pragma unroll
    for (int h2 = 0; h2 < 2; ++h2) {
        const int qi = qt*QIB + w*8 + h2*4 + g16;
        #pragma unroll
        for (int r = 0; r < 4; ++r) {
            const float inv = 1.f / fmaxf(lrun[h2][r], 1e-10f);
            float* op = out + (((size_t)(s*QL + qi)*NH + h)*NG + r)*DH;
            #pragma unroll
            for (int f = 0; f < 8; ++f)
                op[f*16 + c16] = oacc[h2][f][r] * inv;
        }
    }
}

extern "C" void kernel_launch(void* const* d_in, const int* in_sizes, int n_in,
                              void* d_out, int out_size, void* d_ws, size_t ws_size,
                              hipStream_t stream) {
    (void)in_sizes; (void)n_in; (void)d_ws; (void)ws_size; (void)out_size;
    const float* q         = (const float*)d_in[0];
    const float* kv_pages  = (const float*)d_in[1];
    const int*   kv_lens   = (const int*)d_in[2];
    const int*   page_idx  = (const int*)d_in[3];
    float* out = (float*)d_out;

    dim3 grid(QL/QIB, NH, NSEQ);   // (4, 8, 16) = 512 blocks x 256 threads
    rpa_fwd<<<grid, 256, 0, stream>>>(q, kv_pages, kv_lens, page_idx, out);
}

// Round 7
// 136.510 us; speedup vs baseline: 1.0108x; 1.0108x over previous
//
#include <hip/hip_runtime.h>

typedef _Float16 f16;
typedef __attribute__((ext_vector_type(8))) _Float16 f16x8;
typedef __attribute__((ext_vector_type(4))) float f32x4;

#define NSEQ 16
#define QL   128
#define NH   8
#define NG   4
#define DH   128
#define PGSZ 64
#define PPS  16
#define KT   64      // kv tile == page size (one scalar page lookup per tile)
#define QIB  32      // query indices per block
#define THR_DEFER 11.0f   // defer-max threshold in log2 domain (~7.6 nats)

// Barrier with LDS-visibility only (no vmcnt drain): in-flight global
// prefetch loads stay outstanding across it.
__device__ __forceinline__ void bar_lds() {
    asm volatile("s_waitcnt lgkmcnt(0)" ::: "memory");
    __builtin_amdgcn_s_barrier();
    asm volatile("" ::: "memory");
}

// DPP row_ror:N within 16-lane rows — cross-lane reduce on the VALU pipe,
// zero DS-pipe traffic (replaces ds_swizzle-based __shfl_xor).
template<int N>
__device__ __forceinline__ float rowror(float x) {
    int t = __builtin_amdgcn_update_dpp(__float_as_int(x), __float_as_int(x),
                                        0x120 | N, 0xF, 0xF, false);
    return __int_as_float(t);
}
__device__ __forceinline__ float rmax16(float x) {
    x = fmaxf(x, rowror<1>(x));
    x = fmaxf(x, rowror<2>(x));
    x = fmaxf(x, rowror<4>(x));
    x = fmaxf(x, rowror<8>(x));
    return x;
}
__device__ __forceinline__ float rsum16(float x) {
    x += rowror<1>(x);
    x += rowror<2>(x);
    x += rowror<4>(x);
    x += rowror<8>(x);
    return x;
}

__device__ __forceinline__ float fexp2(float x) {
    return __builtin_amdgcn_exp2f(x);
}

__global__ __launch_bounds__(256, 2)
void rpa_fwd(const float* __restrict__ q,
             const float* __restrict__ kv_pages,
             const int* __restrict__ kv_lens,
             const int* __restrict__ page_indices,
             float* __restrict__ out)
{
    const int tid  = threadIdx.x;
    const int w    = tid >> 6;    // wave 0..3, owns q-rows [w*32, w*32+32)
    const int lane = tid & 63;
    const int c16  = lane & 15;
    const int g16  = lane >> 4;

    const int qt = blockIdx.x;    // 0..3
    const int h  = blockIdx.y;    // 0..7
    const int s  = blockIdx.z;    // 0..15

    const int kv_len = kv_lens[s];
    const int kv_end = kv_len - QL + qt*QIB + QIB;   // exclusive kv bound
    const int ntile  = (kv_end + KT - 1) >> 6;

    // Un-padded rows + XOR slot swizzle (slot ^= row&7) -> conflict-free b128
    __shared__ f16 Klds [KT][DH];      // 64 rows x 256B
    __shared__ f16 VTlds[DH][KT];      // 128 rows x 128B (V transposed)
    __shared__ f16 Plds [4][QIB][KT];  // per-wave P, 32 rows x 128B

    // staging maps (256 threads)
    const int kr  = tid >> 2;          // K row 0..63
    const int kq  = (tid & 3) * 32;    // K f32 col base (32 floats/thread)
    const int vp  = tid & 31;          // V kv-pair -> kv = 2vp, 2vp+1
    const int vd0 = (tid >> 5) * 16;   // V d base (16 d/thread)

    // ---- Q fragments for 2 q-halves, pre-scaled by (1/sqrt(D))*log2(e)
    f16x8 qfrag[2][4];
    {
        const float sc = 0.08838834764831845f * 1.4426950408889634f;
        #pragma unroll
        for (int h2 = 0; h2 < 2; ++h2) {
            const int rowA = h2*16 + c16;
            const int qiA  = qt*QIB + w*8 + (rowA >> 2);
            const int gA   = rowA & 3;
            const float* qp = q + (((size_t)(s*QL + qiA)*NH + h)*NG + gA)*DH;
            #pragma unroll
            for (int sl = 0; sl < 4; ++sl) {
                const float* p = qp + sl*32 + g16*8;
                f32x4 a = *(const f32x4*)p;
                f32x4 b = *(const f32x4*)(p + 4);
                f16x8 f;
                f[0]=(f16)(a[0]*sc); f[1]=(f16)(a[1]*sc); f[2]=(f16)(a[2]*sc); f[3]=(f16)(a[3]*sc);
                f[4]=(f16)(b[0]*sc); f[5]=(f16)(b[1]*sc); f[6]=(f16)(b[2]*sc); f[7]=(f16)(b[3]*sc);
                qfrag[h2][sl] = f;
            }
        }
    }

    // causal positions: D-frag row (h2,g16,r) -> qi = qt*32 + w*8 + h2*4 + g16
    int qp2[2];
    qp2[0] = kv_len - QL + qt*QIB + w*8 + g16;
    qp2[1] = qp2[0] + 4;
    const int qp_wave_min = kv_len - QL + qt*QIB + w*8;

    f32x4 oacc[2][8];
    #pragma unroll
    for (int h2 = 0; h2 < 2; ++h2)
        #pragma unroll
        for (int f = 0; f < 8; ++f) oacc[h2][f] = f32x4{0.f,0.f,0.f,0.f};
    float mrun[2][4], lrun[2][4];
    #pragma unroll
    for (int h2 = 0; h2 < 2; ++h2)
        #pragma unroll
        for (int r = 0; r < 4; ++r) { mrun[h2][r] = -1e30f; lrun[h2][r] = 0.f; }

    // prefetch regs: tile t+1 in flight across compute of tile t
    f32x4 kld[8], vld[8];

#define LOAD_TILE(T) do {                                                                \
        const int pg_ = page_indices[s*PPS + (T)];                                      \
        const float* kb_ = kv_pages + (((size_t)pg_*PGSZ + kr)*(2*NH) + h)*DH + kq;     \
        _Pragma("unroll")                                                                \
        for (int i_ = 0; i_ < 8; ++i_) kld[i_] = *(const f32x4*)(kb_ + i_*4);           \
        const float* vb_ = kv_pages + (((size_t)pg_*PGSZ + 2*vp)*(2*NH) + NH + h)*DH + vd0; \
        _Pragma("unroll")                                                                \
        for (int i_ = 0; i_ < 4; ++i_) vld[i_]   = *(const f32x4*)(vb_ + i_*4);         \
        _Pragma("unroll")                                                                \
        for (int i_ = 0; i_ < 4; ++i_) vld[4+i_] = *(const f32x4*)(vb_ + 2*NH*DH + i_*4); \
    } while (0)
    // NOTE: rows >= kv_end load real (valid) memory within the page; those kv
    // are always causally masked (kv > q_pos for every row in block), so no
    // zero-fill is needed.

#define WRITE_TILE() do {                                                                \
        _Pragma("unroll")                                                                \
        for (int i_ = 0; i_ < 4; ++i_) {                                                 \
            f16x8 kk_;                                                                   \
            _Pragma("unroll")                                                            \
            for (int j_ = 0; j_ < 4; ++j_) {                                             \
                kk_[j_]   = (f16)kld[2*i_][j_];                                          \
                kk_[4+j_] = (f16)kld[2*i_+1][j_];                                        \
            }                                                                            \
            const int slot_ = (((tid&3)*4 + i_) ^ (kr & 7));                             \
            *(f16x8*)((char*)&Klds[0][0] + kr*256 + (slot_<<4)) = kk_;                   \
        }                                                                                \
        _Pragma("unroll")                                                                \
        for (int j_ = 0; j_ < 16; ++j_) {                                                \
            union { f16 hh[2]; int u; } pk_;                                             \
            pk_.hh[0] = (f16)vld[j_>>2][j_&3];                                           \
            pk_.hh[1] = (f16)vld[4+(j_>>2)][j_&3];                                       \
            *(int*)((char*)&VTlds[0][0] + (vd0+j_)*128 + ((4*vp) ^ ((j_&7)<<4))) = pk_.u;\
        }                                                                                \
    } while (0)

    LOAD_TILE(0);

    for (int t = 0; t < ntile; ++t) {
        const int kv0 = t << 6;

        WRITE_TILE();                       // vmcnt waits on prefetch regs here
        bar_lds();                          // stage visible; globals stay in flight
        if (t + 1 < ntile) LOAD_TILE(t+1);  // issue next tile, hidden under compute

        // ---- QK^T: 32 q-rows x 64 kv; 16 K reads shared across both q-halves
        f32x4 sacc[2][4];
        #pragma unroll
        for (int h2 = 0; h2 < 2; ++h2)
            #pragma unroll
            for (int ks = 0; ks < 4; ++ks) sacc[h2][ks] = f32x4{0.f,0.f,0.f,0.f};
        #pragma unroll
        for (int ks = 0; ks < 4; ++ks) {
            #pragma unroll
            for (int sl = 0; sl < 4; ++sl) {
                f16x8 kf = *(const f16x8*)((const char*)&Klds[0][0]
                            + (ks*16 + c16)*256 + ((((sl<<2)|g16) ^ (c16&7))<<4));
                sacc[0][ks] = __builtin_amdgcn_mfma_f32_16x16x32_f16(qfrag[0][sl], kf, sacc[0][ks], 0,0,0);
                sacc[1][ks] = __builtin_amdgcn_mfma_f32_16x16x32_f16(qfrag[1][sl], kf, sacc[1][ks], 0,0,0);
            }
        }

        // ---- causal mask (wave-uniform skip for interior tiles)
        if (kv0 + KT - 1 > qp_wave_min) {
            #pragma unroll
            for (int h2 = 0; h2 < 2; ++h2)
                #pragma unroll
                for (int ks = 0; ks < 4; ++ks) {
                    const bool ok = (kv0 + ks*16 + c16) <= qp2[h2];
                    #pragma unroll
                    for (int r = 0; r < 4; ++r)
                        sacc[h2][ks][r] = ok ? sacc[h2][ks][r] : -1e30f;
                }
        }

        // ---- online softmax (exp2 domain), DPP reduces, defer-max rescale
        float mt[2][4];
        bool need = false;
        #pragma unroll
        for (int h2 = 0; h2 < 2; ++h2)
            #pragma unroll
            for (int r = 0; r < 4; ++r) {
                float a = fmaxf(fmaxf(sacc[h2][0][r], sacc[h2][1][r]),
                                fmaxf(sacc[h2][2][r], sacc[h2][3][r]));
                a = rmax16(a);
                mt[h2][r] = a;
                need = need || (a > mrun[h2][r] + THR_DEFER);
            }
        if (__any(need)) {
            #pragma unroll
            for (int h2 = 0; h2 < 2; ++h2)
                #pragma unroll
                for (int r = 0; r < 4; ++r) {
                    const float mn  = fmaxf(mrun[h2][r], mt[h2][r]);
                    const float fac = fexp2(mrun[h2][r] - mn);
                    lrun[h2][r] *= fac;
                    mrun[h2][r] = mn;
                    #pragma unroll
                    for (int f = 0; f < 8; ++f) oacc[h2][f] *= fac;
                }
        }
        #pragma unroll
        for (int h2 = 0; h2 < 2; ++h2)
            #pragma unroll
            for (int r = 0; r < 4; ++r) {
                const float m = mrun[h2][r];
                float p0 = fexp2(sacc[h2][0][r] - m);
                float p1 = fexp2(sacc[h2][1][r] - m);
                float p2 = fexp2(sacc[h2][2][r] - m);
                float p3 = fexp2(sacc[h2][3][r] - m);
                lrun[h2][r] += rsum16((p0 + p1) + (p2 + p3));
                const int prow = h2*16 + g16*4 + r;
                char* pb = (char*)&Plds[w][0][0] + prow*128;
                const int key = (prow & 7) << 4;
                *(f16*)(pb + ((0*32 + 2*c16) ^ key)) = (f16)p0;
                *(f16*)(pb + ((1*32 + 2*c16) ^ key)) = (f16)p1;
                *(f16*)(pb + ((2*32 + 2*c16) ^ key)) = (f16)p2;
                *(f16*)(pb + ((3*32 + 2*c16) ^ key)) = (f16)p3;
            }

        // ---- P @ V: 16 V reads shared across both q-halves
        #pragma unroll
        for (int kvh = 0; kvh < 2; ++kvh) {
            f16x8 pf0 = *(const f16x8*)((const char*)&Plds[w][0][0]
                         + (0*16 + c16)*128 + ((((kvh<<2)|g16) ^ (c16&7))<<4));
            f16x8 pf1 = *(const f16x8*)((const char*)&Plds[w][0][0]
                         + (1*16 + c16)*128 + ((((kvh<<2)|g16) ^ (c16&7))<<4));
            #pragma unroll
            for (int f = 0; f < 8; ++f) {
                f16x8 vf = *(const f16x8*)((const char*)&VTlds[0][0]
                            + (f*16 + c16)*128 + ((((kvh<<2)|g16) ^ (c16&7))<<4));
                oacc[0][f] = __builtin_amdgcn_mfma_f32_16x16x32_f16(pf0, vf, oacc[0][f], 0,0,0);
                oacc[1][f] = __builtin_amdgcn_mfma_f32_16x16x32_f16(pf1, vf, oacc[1][f], 0,0,0);
            }
        }

        bar_lds();   // all reads of K/VT done before next WRITE_TILE
    }

    // ---- epilogue
    #pragma unroll
    for (int h2 = 0; h2 < 2; ++h2) {
        const int qi = qt*QIB + w*8 + h2*4 + g16;
        #pragma unroll
        for (int r = 0; r < 4; ++r) {
            const float inv = 1.f / fmaxf(lrun[h2][r], 1e-10f);
            float* op = out + (((size_t)(s*QL + qi)*NH + h)*NG + r)*DH;
            #pragma unroll
            for (int f = 0; f < 8; ++f)
                op[f*16 + c16] = oacc[h2][f][r] * inv;
        }
    }
}

extern "C" void kernel_launch(void* const* d_in, const int* in_sizes, int n_in,
                              void* d_out, int out_size, void* d_ws, size_t ws_size,
                              hipStream_t stream) {
    (void)in_sizes; (void)n_in; (void)d_ws; (void)ws_size; (void)out_size;
    const float* q         = (const float*)d_in[0];
    const float* kv_pages  = (const float*)d_in[1];
    const int*   kv_lens   = (const int*)d_in[2];
    const int*   page_idx  = (const int*)d_in[3];
    float* out = (float*)d_out;

    dim3 grid(QL/QIB, NH, NSEQ);   // (4, 8, 16) = 512 blocks x 256 threads
    rpa_fwd<<<grid, 256, 0, stream>>>(q, kv_pages, kv_lens, page_idx, out);
}